// Round 16
// baseline (274.764 us; speedup 1.0000x reference)
//
#include <hip/hip_runtime.h>
#include <cstdint>
#include <cstddef>

#define NN 100000
#define NE 1000000
#define GEMM_BLOCKS 1563           // (NN+63)/64   layer-1 gemm slices
#define TICKET_BLOCKS 3907         // (NE+255)/256 ticket slices (ILP-1)
#define MERGED_BLOCKS 5470         // GEMM_BLOCKS + TICKET_BLOCKS
#define GEMM2_BLOCKS 782           // (NN+127)/128 512-thread GEMMs
#define TICKET4_BLOCKS 977         // ceil(NE/4/256) for ILP-4 place
#define NB_SCAN 391                // (NN+255)/256
#define NF_SCAN 196                // (NN+1+511)/512
#define LOG2E 1.4426950408896340736f

typedef unsigned int uint;
typedef unsigned short ushort;
typedef __attribute__((ext_vector_type(8))) short bfrag;   // 8 bf16 = 4 VGPR
typedef __attribute__((ext_vector_type(4))) float f32x4;

__device__ __forceinline__ ushort f2bf(float f){
  uint u = __float_as_uint(f);
  u += 0x7fffu + ((u >> 16) & 1u);     // round-to-nearest-even
  return (ushort)(u >> 16);
}
__device__ __forceinline__ float bflo(uint p){ return __uint_as_float(p << 16); }
__device__ __forceinline__ float bfhi(uint p){ return __uint_as_float(p & 0xffff0000u); }

// ---------------- prep0: weight packs + zero cnt4/dbin (replaces 2 memsets) ----------------

__device__ __forceinline__ void bfrag_body(const float* __restrict__ B1, const float* __restrict__ B2,
                                           int n1, int n2, int NT, ushort* __restrict__ out, int i){
  if (i >= NT*4*64) return;
  int l = i & 63, ks = (i>>6)&3, nt = i>>8;
  int col = nt*16 + (l&15);
  int k0  = ks*32 + (l>>4)*8;
  const float* B; int stride, c;
  if (col < n1){ B = B1; stride = n1; c = col; }
  else         { B = B2; stride = n2; c = col - n1; }
  ushort v[8];
  #pragma unroll
  for (int j=0;j<8;j++) v[j] = f2bf(B[(size_t)(k0+j)*stride + c]);
  uint4 pk;
  pk.x = (uint)v[0] | ((uint)v[1]<<16);
  pk.y = (uint)v[2] | ((uint)v[3]<<16);
  pk.z = (uint)v[4] | ((uint)v[5]<<16);
  pk.w = (uint)v[6] | ((uint)v[7]<<16);
  *(uint4*)(out + (size_t)i*8) = pk;
}

__global__ __launch_bounds__(256) void k_prep0(const float* __restrict__ W1, const float* __restrict__ W2,
                                               const float* __restrict__ W3, const float* __restrict__ res3,
                                               ushort* __restrict__ Bf1, ushort* __restrict__ Bf2,
                                               ushort* __restrict__ Bf3,
                                               int* __restrict__ cnt4, int* __restrict__ dbin){
  int r = blockIdx.x, t = threadIdx.x;
  if (r < 8)       bfrag_body(W1, nullptr, 128, 0, 8, Bf1, r*256 + t);
  else if (r < 16) bfrag_body(W2, nullptr, 128, 0, 8, Bf2, (r-8)*256 + t);
  else if (r < 20) bfrag_body(W3, res3,    32, 32, 4, Bf3, (r-16)*256 + t);
  else if (r < 20 + NB_SCAN){
    int i = (r-20)*256 + t;
    if (i < NN) ((int4*)cnt4)[i] = make_int4(0,0,0,0);
  } else {
    dbin[t] = 0;
  }
}

// ---------------- layer-1 GEMM (fused cast, no LDS) INTERLEAVED 2:5 with ticket pass ----------------

__global__ __launch_bounds__(256, 4)
void k_gemm1_ticket(const float* __restrict__ x, const ushort* __restrict__ Bf1,
                    ushort* __restrict__ featb,
                    const float* __restrict__ al, const float* __restrict__ ar,
                    float* __restrict__ el, float* __restrict__ er,
                    const int* __restrict__ dst, int* __restrict__ cnt4, int* __restrict__ tick){
  long b = blockIdx.x;
  int t = threadIdx.x;
  int g_lo = (int)( b      * GEMM_BLOCKS / MERGED_BLOCKS);
  int g_hi = (int)((b + 1) * GEMM_BLOCKS / MERGED_BLOCKS);
  if (g_hi == g_lo){
    // ticket slice (ILP-1: one returning atomic per thread)
    int e = (int)(b - g_lo)*256 + t;
    if (e < NE) tick[e] = atomicAdd(&cnt4[(uint)dst[e]*4u + (e & 3)], 1);
    return;
  }
  int bid = g_lo;

  int l = t & 63, w = t >> 6;
  int rw = bid*64 + w*16;
  int c = l & 15, g = l >> 4;

  f32x4 acc[8];
  #pragma unroll
  for (int nt=0;nt<8;nt++) acc[nt] = (f32x4){0.f,0.f,0.f,0.f};

  int rowA = rw + c; if (rowA >= NN) rowA = NN-1;
  const float* Ap = x + (size_t)rowA*128 + g*8;
  const bfrag* Bp = (const bfrag*)Bf1;

  #pragma unroll
  for (int ks=0; ks<4; ++ks){
    float4 f0 = *(const float4*)(Ap + ks*32);
    float4 f1 = *(const float4*)(Ap + ks*32 + 4);
    bfrag a;
    a[0]=(short)f2bf(f0.x); a[1]=(short)f2bf(f0.y); a[2]=(short)f2bf(f0.z); a[3]=(short)f2bf(f0.w);
    a[4]=(short)f2bf(f1.x); a[5]=(short)f2bf(f1.y); a[6]=(short)f2bf(f1.z); a[7]=(short)f2bf(f1.w);
    #pragma unroll
    for (int nt=0; nt<8; ++nt){
      bfrag bb = Bp[(nt*4+ks)*64 + l];
      acc[nt] = __builtin_amdgcn_mfma_f32_16x16x32_bf16(a, bb, acc[nt], 0, 0, 0);
    }
  }

  float alv[4][2], arv[4][2];
  #pragma unroll
  for (int h=0;h<4;h++){
    alv[h][0]=al[h*32+c]*LOG2E;    arv[h][0]=ar[h*32+c]*LOG2E;
    alv[h][1]=al[h*32+16+c]*LOG2E; arv[h][1]=ar[h*32+16+c]*LOG2E;
  }

  #pragma unroll
  for (int reg=0; reg<4; ++reg){
    int row = rw + g*4 + reg;
    bool ok = row < NN;
    #pragma unroll
    for (int h=0;h<4;h++){
      float pl = acc[2*h][reg]*alv[h][0] + acc[2*h+1][reg]*alv[h][1];
      float pr = acc[2*h][reg]*arv[h][0] + acc[2*h+1][reg]*arv[h][1];
      #pragma unroll
      for (int off=1; off<16; off<<=1){ pl += __shfl_xor(pl,off); pr += __shfl_xor(pr,off); }
      if (ok && c==0){ el[(size_t)row*4 + h] = pl; er[(size_t)row*4 + h] = pr; }
    }
    if (ok){
      #pragma unroll
      for (int nt=0; nt<8; ++nt)
        featb[(size_t)row*128 + nt*16 + c] = f2bf(acc[nt][reg]);
    }
  }
}

// ---------------- scan_local + degree histogram (merged) ----------------

__global__ __launch_bounds__(256) void k_scan_local(const int* __restrict__ cnt4, int* __restrict__ shoff,
                                                    int* __restrict__ rowptr, int* __restrict__ bsum,
                                                    int* __restrict__ dbin){
  __shared__ int sm[256];
  __shared__ int lh[256];
  int t = threadIdx.x;
  lh[t] = 0;
  int i = blockIdx.x*256 + t;
  int v = 0;
  if (i < NN){
    int4 cc = ((const int4*)cnt4)[i];
    v = cc.x + cc.y + cc.z + cc.w;
    int4 so;
    so.x = 0; so.y = cc.x; so.z = cc.x + cc.y; so.w = cc.x + cc.y + cc.z;
    ((int4*)shoff)[i] = so;
  }
  sm[t] = v;
  __syncthreads();
  if (i < NN) atomicAdd(&lh[v > 255 ? 255 : v], 1);   // degree histogram
  for (int off=1; off<256; off<<=1){
    int u = (t>=off) ? sm[t-off] : 0;
    __syncthreads();
    sm[t] += u;
    __syncthreads();
  }
  if (i < NN) rowptr[i] = sm[t] - v;
  if (t == 255) bsum[blockIdx.x] = sm[255];
  __syncthreads();
  if (lh[t] > 0) atomicAdd(&dbin[t], lh[t]);
}

// ---------------- scan_finish + dscan (merged; last block scans dbin) ----------------

__global__ __launch_bounds__(512) void k_scan_finish(int* __restrict__ rowptr, const int* __restrict__ bsum,
                                                     int* __restrict__ dbin){
  __shared__ int sm[512];
  int t = threadIdx.x;
  if (blockIdx.x == NF_SCAN){
    int v = (t < 256) ? dbin[t] : 0;
    sm[t] = v;
    __syncthreads();
    for (int off=1; off<512; off<<=1){
      int u = (t>=off) ? sm[t-off] : 0;
      __syncthreads();
      sm[t] += u;
      __syncthreads();
    }
    if (t < 256) dbin[t] = sm[t] - v;   // exclusive
    return;
  }
  __shared__ int ex[512];
  int v = (t < NB_SCAN) ? bsum[t] : 0;
  sm[t] = v;
  __syncthreads();
  for (int off=1; off<512; off<<=1){
    int u = (t>=off) ? sm[t-off] : 0;
    __syncthreads();
    sm[t] += u;
    __syncthreads();
  }
  ex[t] = sm[t] - v;
  __syncthreads();
  int i = blockIdx.x*512 + t;
  if (i < NN) rowptr[i] += ex[i>>8];
  else if (i == NN) rowptr[NN] = NE;
}

// ---------------- CSR placement (ILP-4) MERGED with perm scatter ----------------

__global__ __launch_bounds__(256) void k_place_dscat(const int* __restrict__ src, const int* __restrict__ dst,
                                                     const int* __restrict__ rowptr, const int* __restrict__ shoff,
                                                     const int* __restrict__ tick, int* __restrict__ csr,
                                                     int* __restrict__ dbin, int* __restrict__ perm){
  int bid = blockIdx.x, t = threadIdx.x;
  if (bid < TICKET4_BLOCKS){
    int idx = bid*256 + t;
    if (idx < NE/4){
      int e0 = idx*4;
      int4 s4 = *(const int4*)(src + e0);
      int4 d4 = *(const int4*)(dst + e0);
      int4 t4 = *(const int4*)(tick + e0);
      csr[rowptr[d4.x] + shoff[(uint)d4.x*4u + 0u] + t4.x] = s4.x;
      csr[rowptr[d4.y] + shoff[(uint)d4.y*4u + 1u] + t4.y] = s4.y;
      csr[rowptr[d4.z] + shoff[(uint)d4.z*4u + 2u] + t4.z] = s4.z;
      csr[rowptr[d4.w] + shoff[(uint)d4.w*4u + 3u] + t4.w] = s4.w;
    }
  } else {
    __shared__ int lh[256];
    __shared__ int lbase[256];
    lh[t] = 0;
    __syncthreads();
    int n = (bid - TICKET4_BLOCKS)*256 + t;
    int bin = -1, lticket = 0;
    if (n < NN){
      int deg = rowptr[n+1] - rowptr[n];
      bin = deg > 255 ? 255 : deg;
      lticket = atomicAdd(&lh[bin], 1);
    }
    __syncthreads();
    if (lh[t] > 0) lbase[t] = atomicAdd(&dbin[t], lh[t]);
    __syncthreads();
    if (n < NN) perm[lbase[bin] + lticket] = n;
  }
}

// ---------------- MFMA GEMM, K=128, 512 threads, 128 rows/block, B in LDS ----------------

template<int NT, int NTF, int H>
__global__ __launch_bounds__(512) void k_gemm_mfma(const ushort* __restrict__ Ab, const ushort* __restrict__ Bf,
                                                   ushort* __restrict__ featb, float* __restrict__ Cres,
                                                   const float* __restrict__ al, const float* __restrict__ ar,
                                                   float* __restrict__ el, float* __restrict__ er, int M){
  __shared__ ushort Bs[NT*2048];
  int t = threadIdx.x;
  #pragma unroll
  for (int i=0; i<NT/2; ++i)
    ((uint4*)Bs)[i*512 + t] = ((const uint4*)Bf)[i*512 + t];
  __syncthreads();

  int l = t & 63, w = t >> 6;              // w = 0..7
  int rw = blockIdx.x*128 + w*16;
  int c = l & 15, g = l >> 4;

  f32x4 acc[NT];
  #pragma unroll
  for (int nt=0;nt<NT;nt++) acc[nt] = (f32x4){0.f,0.f,0.f,0.f};

  int rowA = rw + c; if (rowA >= M) rowA = M-1;
  const ushort* Ap = Ab + (size_t)rowA*128 + g*8;
  const bfrag* Bp = (const bfrag*)Bs;

  #pragma unroll
  for (int ks=0; ks<4; ++ks){
    bfrag a = *(const bfrag*)(Ap + ks*32);
    #pragma unroll
    for (int nt=0; nt<NT; ++nt){
      bfrag b = Bp[(nt*4+ks)*64 + l];
      acc[nt] = __builtin_amdgcn_mfma_f32_16x16x32_bf16(a, b, acc[nt], 0, 0, 0);
    }
  }

  float alv[H][2], arv[H][2];
  #pragma unroll
  for (int h=0;h<H;h++){
    alv[h][0]=al[h*32+c]*LOG2E;    arv[h][0]=ar[h*32+c]*LOG2E;
    alv[h][1]=al[h*32+16+c]*LOG2E; arv[h][1]=ar[h*32+16+c]*LOG2E;
  }

  #pragma unroll
  for (int reg=0; reg<4; ++reg){
    int row = rw + g*4 + reg;
    bool ok = row < M;
    #pragma unroll
    for (int h=0;h<H;h++){
      float pl = acc[2*h][reg]*alv[h][0] + acc[2*h+1][reg]*alv[h][1];
      float pr = acc[2*h][reg]*arv[h][0] + acc[2*h+1][reg]*arv[h][1];
      #pragma unroll
      for (int off=1; off<16; off<<=1){ pl += __shfl_xor(pl,off); pr += __shfl_xor(pr,off); }
      if (ok && c==0){ el[(size_t)row*H + h] = pl; er[(size_t)row*H + h] = pr; }
    }
    if (ok){
      #pragma unroll
      for (int nt=0; nt<NTF; ++nt)
        featb[(size_t)row*(NTF*16) + nt*16 + c] = f2bf(acc[nt][reg]);
      #pragma unroll
      for (int nt=NTF; nt<NT; ++nt)
        Cres[(size_t)row*((NT-NTF)*16) + (nt-NTF)*16 + c] = acc[nt][reg];
    }
  }
}

// ---------------- aggregation H=4: 4 nodes/wave, 16 lanes/node, no reductions ----------------

template<int RK>
__global__ __launch_bounds__(256) void k_agg4(const int* __restrict__ rowptr, const int* __restrict__ csr,
                                              const int* __restrict__ perm,
                                              const ushort* __restrict__ feat,
                                              const float* __restrict__ el, const float* __restrict__ er,
                                              const void* __restrict__ res, const float* __restrict__ bias,
                                              ushort* __restrict__ out, int act){
  int t = threadIdx.x;
  int l15 = t & 15;
  int node = perm[blockIdx.x*16 + (t>>4)];

  int beg = rowptr[node], deg = rowptr[node+1] - beg;
  int hm = l15 >> 2;
  float erh = er[(size_t)node*4 + hm];
  const int* cp = csr + beg;
  uint fo = (uint)l15*8u;

  float ssum = 0.f;
  float a0=0.f,a1=0.f,a2=0.f,a3=0.f,a4=0.f,a5=0.f,a6=0.f,a7=0.f;

  int ei = 0;
  for (; ei+4 <= deg; ei += 4){
    int s0 = cp[ei], s1 = cp[ei+1], s2 = cp[ei+2], s3 = cp[ei+3];
    uint4 p0 = *(const uint4*)(feat + ((uint)s0*128u + fo));
    uint4 p1 = *(const uint4*)(feat + ((uint)s1*128u + fo));
    uint4 p2 = *(const uint4*)(feat + ((uint)s2*128u + fo));
    uint4 p3 = *(const uint4*)(feat + ((uint)s3*128u + fo));
    float v0 = el[(uint)s0*4u + hm] + erh; v0 = fmaxf(v0, 0.2f*v0);
    float v1 = el[(uint)s1*4u + hm] + erh; v1 = fmaxf(v1, 0.2f*v1);
    float v2 = el[(uint)s2*4u + hm] + erh; v2 = fmaxf(v2, 0.2f*v2);
    float v3 = el[(uint)s3*4u + hm] + erh; v3 = fmaxf(v3, 0.2f*v3);
    float w0 = __builtin_amdgcn_exp2f(v0);
    float w1 = __builtin_amdgcn_exp2f(v1);
    float w2 = __builtin_amdgcn_exp2f(v2);
    float w3 = __builtin_amdgcn_exp2f(v3);
    ssum += (w0 + w1) + (w2 + w3);
    a0 += w0*bflo(p0.x) + w1*bflo(p1.x) + w2*bflo(p2.x) + w3*bflo(p3.x);
    a1 += w0*bfhi(p0.x) + w1*bfhi(p1.x) + w2*bfhi(p2.x) + w3*bfhi(p3.x);
    a2 += w0*bflo(p0.y) + w1*bflo(p1.y) + w2*bflo(p2.y) + w3*bflo(p3.y);
    a3 += w0*bfhi(p0.y) + w1*bfhi(p1.y) + w2*bfhi(p2.y) + w3*bfhi(p3.y);
    a4 += w0*bflo(p0.z) + w1*bflo(p1.z) + w2*bflo(p2.z) + w3*bflo(p3.z);
    a5 += w0*bfhi(p0.z) + w1*bfhi(p1.z) + w2*bfhi(p2.z) + w3*bfhi(p3.z);
    a6 += w0*bflo(p0.w) + w1*bflo(p1.w) + w2*bflo(p2.w) + w3*bflo(p3.w);
    a7 += w0*bfhi(p0.w) + w1*bfhi(p1.w) + w2*bfhi(p2.w) + w3*bfhi(p3.w);
  }
  for (; ei < deg; ++ei){
    int s0 = cp[ei];
    uint4 p0 = *(const uint4*)(feat + ((uint)s0*128u + fo));
    float v0 = el[(uint)s0*4u + hm] + erh; v0 = fmaxf(v0, 0.2f*v0);
    float w0 = __builtin_amdgcn_exp2f(v0);
    ssum += w0;
    a0 += w0*bflo(p0.x); a1 += w0*bfhi(p0.x);
    a2 += w0*bflo(p0.y); a3 += w0*bfhi(p0.y);
    a4 += w0*bflo(p0.z); a5 += w0*bfhi(p0.z);
    a6 += w0*bflo(p0.w); a7 += w0*bfhi(p0.w);
  }

  float inv = (deg > 0) ? 1.f/ssum : 0.f;
  float o0=a0*inv, o1=a1*inv, o2=a2*inv, o3=a3*inv;
  float o4=a4*inv, o5=a5*inv, o6=a6*inv, o7=a7*inv;
  if (RK == 1){
    uint4 rv = *(const uint4*)((const ushort*)res + (size_t)node*128 + fo);
    o0 += bflo(rv.x); o1 += bfhi(rv.x); o2 += bflo(rv.y); o3 += bfhi(rv.y);
    o4 += bflo(rv.z); o5 += bfhi(rv.z); o6 += bflo(rv.w); o7 += bfhi(rv.w);
  }
  float4 bv0 = *(const float4*)(bias + l15*8);
  float4 bv1 = *(const float4*)(bias + l15*8 + 4);
  o0 += bv0.x; o1 += bv0.y; o2 += bv0.z; o3 += bv0.w;
  o4 += bv1.x; o5 += bv1.y; o6 += bv1.z; o7 += bv1.w;
  if (act){
    o0 = (o0>0.f)?o0:__expf(o0)-1.f;
    o1 = (o1>0.f)?o1:__expf(o1)-1.f;
    o2 = (o2>0.f)?o2:__expf(o2)-1.f;
    o3 = (o3>0.f)?o3:__expf(o3)-1.f;
    o4 = (o4>0.f)?o4:__expf(o4)-1.f;
    o5 = (o5>0.f)?o5:__expf(o5)-1.f;
    o6 = (o6>0.f)?o6:__expf(o6)-1.f;
    o7 = (o7>0.f)?o7:__expf(o7)-1.f;
  }
  uint4 pk;
  pk.x = (uint)f2bf(o0) | ((uint)f2bf(o1)<<16);
  pk.y = (uint)f2bf(o2) | ((uint)f2bf(o3)<<16);
  pk.z = (uint)f2bf(o4) | ((uint)f2bf(o5)<<16);
  pk.w = (uint)f2bf(o6) | ((uint)f2bf(o7)<<16);
  *(uint4*)(out + (size_t)node*128 + fo) = pk;
}

// ---------------- aggregation H=1: 8 nodes/wave, 8 lanes/node ----------------

__global__ __launch_bounds__(256) void k_agg1(const int* __restrict__ rowptr, const int* __restrict__ csr,
                                              const int* __restrict__ perm,
                                              const ushort* __restrict__ feat,
                                              const float* __restrict__ el, const float* __restrict__ er,
                                              const float* __restrict__ res, const float* __restrict__ bias,
                                              float* __restrict__ h3){
  int t = threadIdx.x;
  int l7 = t & 7;
  int node = perm[blockIdx.x*32 + (t>>3)];

  int beg = rowptr[node], deg = rowptr[node+1] - beg;
  float er0 = er[node];
  const int* cp = csr + beg;
  uint fo = (uint)l7*4u;

  float ssum = 0.f, a0=0.f, a1=0.f, a2=0.f, a3=0.f;
  int ei = 0;
  for (; ei+2 <= deg; ei += 2){
    int s0 = cp[ei], s1 = cp[ei+1];
    uint2 p0 = *(const uint2*)(feat + ((uint)s0*32u + fo));
    uint2 p1 = *(const uint2*)(feat + ((uint)s1*32u + fo));
    float v0 = el[s0] + er0; v0 = fmaxf(v0, 0.2f*v0);
    float v1 = el[s1] + er0; v1 = fmaxf(v1, 0.2f*v1);
    float w0 = __builtin_amdgcn_exp2f(v0);
    float w1 = __builtin_amdgcn_exp2f(v1);
    ssum += w0 + w1;
    a0 += w0*bflo(p0.x) + w1*bflo(p1.x);
    a1 += w0*bfhi(p0.x) + w1*bfhi(p1.x);
    a2 += w0*bflo(p0.y) + w1*bflo(p1.y);
    a3 += w0*bfhi(p0.y) + w1*bfhi(p1.y);
  }
  if (ei < deg){
    int s0 = cp[ei];
    uint2 p0 = *(const uint2*)(feat + ((uint)s0*32u + fo));
    float v0 = el[s0] + er0; v0 = fmaxf(v0, 0.2f*v0);
    float w0 = __builtin_amdgcn_exp2f(v0);
    ssum += w0;
    a0 += w0*bflo(p0.x); a1 += w0*bfhi(p0.x);
    a2 += w0*bflo(p0.y); a3 += w0*bfhi(p0.y);
  }

  float inv = (deg > 0) ? 1.f/ssum : 0.f;
  float4 rv = *(const float4*)(res + (size_t)node*32 + fo);
  float4 bv = *(const float4*)(bias + fo);
  float4 ov;
  ov.x = a0*inv + rv.x + bv.x;
  ov.y = a1*inv + rv.y + bv.y;
  ov.z = a2*inv + rv.z + bv.z;
  ov.w = a3*inv + rv.w + bv.w;
  *(float4*)(h3 + (size_t)node*32 + fo) = ov;
}

// ---------------- final FC: out[N,40] = h[N,32] @ Wfc[32,40] + bfc ----------------

__global__ __launch_bounds__(256) void k_fc(const float* __restrict__ h, const float* __restrict__ W,
                                            const float* __restrict__ b, float* __restrict__ out){
  __shared__ float Ws[32*40];
  __shared__ float Hs[64][33];
  __shared__ float bs[40];
  int t = threadIdx.x;
  for (int i=t; i<1280; i+=256) Ws[i] = W[i];
  if (t < 40) bs[t] = b[t];
  int n0 = blockIdx.x*64;
  for (int idx=t; idx<512; idx+=256){
    int r = idx>>3, c4 = idx&7;
    float4 v;
    if (n0 + r < NN) v = *(const float4*)(h + (size_t)(n0+r)*32 + c4*4);
    else v = make_float4(0.f,0.f,0.f,0.f);
    Hs[r][c4*4+0]=v.x; Hs[r][c4*4+1]=v.y; Hs[r][c4*4+2]=v.z; Hs[r][c4*4+3]=v.w;
  }
  __syncthreads();
  int n = t>>2, cg = t&3;
  float acc[10];
  #pragma unroll
  for (int j=0;j<10;j++) acc[j] = 0.f;
  #pragma unroll
  for (int k=0;k<32;k++){
    float hv = Hs[n][k];
    #pragma unroll
    for (int j=0;j<10;j++) acc[j] += hv * Ws[k*40 + cg + 4*j];
  }
  int row = n0 + n;
  if (row < NN){
    #pragma unroll
    for (int j=0;j<10;j++) out[(size_t)row*40 + cg + 4*j] = acc[j] + bs[cg+4*j];
  }
}

// ---------------- launch ----------------

extern "C" void kernel_launch(void* const* d_in, const int* in_sizes, int n_in,
                              void* d_out, int out_size, void* d_ws, size_t ws_size,
                              hipStream_t stream){
  const float* x    = (const float*)d_in[0];
  const int*   src  = (const int*)  d_in[1];
  const int*   dst  = (const int*)  d_in[2];
  const float* W1   = (const float*)d_in[3];
  const float* al1  = (const float*)d_in[4];
  const float* ar1  = (const float*)d_in[5];
  const float* b1   = (const float*)d_in[6];
  const float* W2   = (const float*)d_in[7];
  const float* al2  = (const float*)d_in[8];
  const float* ar2  = (const float*)d_in[9];
  const float* b2   = (const float*)d_in[10];
  const float* W3   = (const float*)d_in[11];
  const float* al3  = (const float*)d_in[12];
  const float* ar3  = (const float*)d_in[13];
  const float* b3   = (const float*)d_in[14];
  const float* res3 = (const float*)d_in[15];
  const float* Wfc  = (const float*)d_in[16];
  const float* bfc  = (const float*)d_in[17];
  float* out = (float*)d_out;

  char* ws = (char*)d_ws;
  size_t o = 0;
  auto alloc = [&](size_t bytes)->char*{
    char* p = ws + o;
    o += (bytes + 255) & ~(size_t)255;
    return p;
  };
  int*    rowptr = (int*)   alloc((size_t)(NN+1)*4);
  int*    cnt4   = (int*)   alloc((size_t)NN*4*4);
  int*    shoff  = (int*)   alloc((size_t)NN*4*4);
  int*    bsum   = (int*)   alloc(512*4);
  int*    dbin   = (int*)   alloc(256*4);
  int*    perm   = (int*)   alloc((size_t)NN*4);
  int*    tick   = (int*)   alloc((size_t)NE*4);
  int*    csr    = (int*)   alloc((size_t)NE*4);
  float*  el     = (float*) alloc((size_t)NN*4*4);
  float*  er     = (float*) alloc((size_t)NN*4*4);
  ushort* featb  = (ushort*)alloc((size_t)NN*128*2);
  ushort* h1b    = (ushort*)alloc((size_t)NN*128*2);
  ushort* h2b    = (ushort*)alloc((size_t)NN*128*2);
  float*  res3p  = (float*) alloc((size_t)NN*32*4);
  float*  h3     = (float*) alloc((size_t)NN*32*4);
  ushort* Bf1    = (ushort*)alloc((size_t)8*4*64*8*2);
  ushort* Bf2    = (ushort*)alloc((size_t)8*4*64*8*2);
  ushort* Bf3    = (ushort*)alloc((size_t)4*4*64*8*2);
  (void)ws_size; (void)n_in; (void)in_sizes; (void)out_size;

  // prep0: weight packs + zero cnt4/dbin
  k_prep0<<<20+NB_SCAN+1, 256, 0, stream>>>(W1, W2, W3, res3, Bf1, Bf2, Bf3, cnt4, dbin);

  // ---- Layer-1 GEMM (fused cast) 2:5-interleaved with ILP-1 ticket atomics ----
  k_gemm1_ticket<<<MERGED_BLOCKS, 256, 0, stream>>>(x, Bf1, featb, al1, ar1, el, er,
                                                    dst, cnt4, tick);

  // scans (+ degree hist folded into scan_local, dscan folded into scan_finish)
  k_scan_local<<<NB_SCAN, 256, 0, stream>>>(cnt4, shoff, rowptr, bsum, dbin);
  k_scan_finish<<<NF_SCAN+1, 512, 0, stream>>>(rowptr, bsum, dbin);

  // CSR placement (ILP-4) overlapped with perm scatter
  k_place_dscat<<<TICKET4_BLOCKS+NB_SCAN, 256, 0, stream>>>(src, dst, rowptr, shoff, tick, csr,
                                                            dbin, perm);

  // ---- Layer 1 aggregation ----
  k_agg4<0><<<NN/16, 256, 0, stream>>>(rowptr, csr, perm, featb, el, er, nullptr, b1, h1b, 1);

  // ---- Layer 2 ----
  k_gemm_mfma<8,8,4><<<GEMM2_BLOCKS, 512, 0, stream>>>(h1b, Bf2, featb, nullptr, al2, ar2, el, er, NN);
  k_agg4<1><<<NN/16, 256, 0, stream>>>(rowptr, csr, perm, featb, el, er, h1b, b2, h2b, 1);

  // ---- Layer 3 ----
  k_gemm_mfma<4,2,1><<<GEMM2_BLOCKS, 512, 0, stream>>>(h2b, Bf3, featb, res3p, al3, ar3, el, er, NN);
  k_agg1<<<NN/32, 256, 0, stream>>>(rowptr, csr, perm, featb, el, er, res3p, b3, h3);
  k_fc<<<GEMM_BLOCKS, 256, 0, stream>>>(h3, Wfc, bfc, out);
}

// Round 17
// 273.264 us; speedup vs baseline: 1.0055x; 1.0055x over previous
//
#include <hip/hip_runtime.h>
#include <cstdint>
#include <cstddef>

#define NN 100000
#define NE 1000000
#define GEMM_BLOCKS 1563           // (NN+63)/64   layer-1 gemm slices
#define TICKET_BLOCKS 3907         // (NE+255)/256 ticket slices (ILP-1)
#define MERGED_BLOCKS 5470         // GEMM_BLOCKS + TICKET_BLOCKS
#define GEMM2_BLOCKS 782           // (NN+127)/128 512-thread GEMMs
#define TICKET4_BLOCKS 977         // ceil(NE/4/256) for ILP-4 place
#define NB_SCAN 391                // (NN+255)/256
#define NF_SCAN 196                // (NN+1+511)/512
#define LOG2E 1.4426950408896340736f

typedef unsigned int uint;
typedef unsigned short ushort;
typedef __attribute__((ext_vector_type(8))) short bfrag;   // 8 bf16 = 4 VGPR
typedef __attribute__((ext_vector_type(4))) float f32x4;

__device__ __forceinline__ ushort f2bf(float f){
  uint u = __float_as_uint(f);
  u += 0x7fffu + ((u >> 16) & 1u);     // round-to-nearest-even
  return (ushort)(u >> 16);
}
__device__ __forceinline__ float bflo(uint p){ return __uint_as_float(p << 16); }
__device__ __forceinline__ float bfhi(uint p){ return __uint_as_float(p & 0xffff0000u); }

// ---------------- prep0: weight packs + zero cnt4/dbin (replaces 2 memsets) ----------------

__device__ __forceinline__ void bfrag_body(const float* __restrict__ B1, const float* __restrict__ B2,
                                           int n1, int n2, int NT, ushort* __restrict__ out, int i){
  if (i >= NT*4*64) return;
  int l = i & 63, ks = (i>>6)&3, nt = i>>8;
  int col = nt*16 + (l&15);
  int k0  = ks*32 + (l>>4)*8;
  const float* B; int stride, c;
  if (col < n1){ B = B1; stride = n1; c = col; }
  else         { B = B2; stride = n2; c = col - n1; }
  ushort v[8];
  #pragma unroll
  for (int j=0;j<8;j++) v[j] = f2bf(B[(size_t)(k0+j)*stride + c]);
  uint4 pk;
  pk.x = (uint)v[0] | ((uint)v[1]<<16);
  pk.y = (uint)v[2] | ((uint)v[3]<<16);
  pk.z = (uint)v[4] | ((uint)v[5]<<16);
  pk.w = (uint)v[6] | ((uint)v[7]<<16);
  *(uint4*)(out + (size_t)i*8) = pk;
}

__global__ __launch_bounds__(256) void k_prep0(const float* __restrict__ W1, const float* __restrict__ W2,
                                               const float* __restrict__ W3, const float* __restrict__ res3,
                                               ushort* __restrict__ Bf1, ushort* __restrict__ Bf2,
                                               ushort* __restrict__ Bf3,
                                               int* __restrict__ cnt4, int* __restrict__ dbin){
  int r = blockIdx.x, t = threadIdx.x;
  if (r < 8)       bfrag_body(W1, nullptr, 128, 0, 8, Bf1, r*256 + t);
  else if (r < 16) bfrag_body(W2, nullptr, 128, 0, 8, Bf2, (r-8)*256 + t);
  else if (r < 20) bfrag_body(W3, res3,    32, 32, 4, Bf3, (r-16)*256 + t);
  else if (r < 20 + NB_SCAN){
    int i = (r-20)*256 + t;
    if (i < NN) ((int4*)cnt4)[i] = make_int4(0,0,0,0);
  } else {
    dbin[t] = 0;
  }
}

// ---------------- layer-1 GEMM (fused cast, no LDS) INTERLEAVED 2:5 with ticket pass ----------------

__global__ __launch_bounds__(256, 4)
void k_gemm1_ticket(const float* __restrict__ x, const ushort* __restrict__ Bf1,
                    ushort* __restrict__ featb,
                    const float* __restrict__ al, const float* __restrict__ ar,
                    float* __restrict__ el, float* __restrict__ er,
                    const int* __restrict__ dst, int* __restrict__ cnt4, int* __restrict__ tick){
  long b = blockIdx.x;
  int t = threadIdx.x;
  int g_lo = (int)( b      * GEMM_BLOCKS / MERGED_BLOCKS);
  int g_hi = (int)((b + 1) * GEMM_BLOCKS / MERGED_BLOCKS);
  if (g_hi == g_lo){
    // ticket slice (ILP-1: one returning atomic per thread)
    int e = (int)(b - g_lo)*256 + t;
    if (e < NE) tick[e] = atomicAdd(&cnt4[(uint)dst[e]*4u + (e & 3)], 1);
    return;
  }
  int bid = g_lo;

  int l = t & 63, w = t >> 6;
  int rw = bid*64 + w*16;
  int c = l & 15, g = l >> 4;

  f32x4 acc[8];
  #pragma unroll
  for (int nt=0;nt<8;nt++) acc[nt] = (f32x4){0.f,0.f,0.f,0.f};

  int rowA = rw + c; if (rowA >= NN) rowA = NN-1;
  const float* Ap = x + (size_t)rowA*128 + g*8;
  const bfrag* Bp = (const bfrag*)Bf1;

  #pragma unroll
  for (int ks=0; ks<4; ++ks){
    float4 f0 = *(const float4*)(Ap + ks*32);
    float4 f1 = *(const float4*)(Ap + ks*32 + 4);
    bfrag a;
    a[0]=(short)f2bf(f0.x); a[1]=(short)f2bf(f0.y); a[2]=(short)f2bf(f0.z); a[3]=(short)f2bf(f0.w);
    a[4]=(short)f2bf(f1.x); a[5]=(short)f2bf(f1.y); a[6]=(short)f2bf(f1.z); a[7]=(short)f2bf(f1.w);
    #pragma unroll
    for (int nt=0; nt<8; ++nt){
      bfrag bb = Bp[(nt*4+ks)*64 + l];
      acc[nt] = __builtin_amdgcn_mfma_f32_16x16x32_bf16(a, bb, acc[nt], 0, 0, 0);
    }
  }

  float alv[4][2], arv[4][2];
  #pragma unroll
  for (int h=0;h<4;h++){
    alv[h][0]=al[h*32+c]*LOG2E;    arv[h][0]=ar[h*32+c]*LOG2E;
    alv[h][1]=al[h*32+16+c]*LOG2E; arv[h][1]=ar[h*32+16+c]*LOG2E;
  }

  #pragma unroll
  for (int reg=0; reg<4; ++reg){
    int row = rw + g*4 + reg;
    bool ok = row < NN;
    #pragma unroll
    for (int h=0;h<4;h++){
      float pl = acc[2*h][reg]*alv[h][0] + acc[2*h+1][reg]*alv[h][1];
      float pr = acc[2*h][reg]*arv[h][0] + acc[2*h+1][reg]*arv[h][1];
      #pragma unroll
      for (int off=1; off<16; off<<=1){ pl += __shfl_xor(pl,off); pr += __shfl_xor(pr,off); }
      if (ok && c==0){ el[(size_t)row*4 + h] = pl; er[(size_t)row*4 + h] = pr; }
    }
    if (ok){
      #pragma unroll
      for (int nt=0; nt<8; ++nt)
        featb[(size_t)row*128 + nt*16 + c] = f2bf(acc[nt][reg]);
    }
  }
}

// ---------------- scan_local + degree histogram (merged) ----------------

__global__ __launch_bounds__(256) void k_scan_local(const int* __restrict__ cnt4, int* __restrict__ shoff,
                                                    int* __restrict__ rowptr, int* __restrict__ bsum,
                                                    int* __restrict__ dbin){
  __shared__ int sm[256];
  __shared__ int lh[256];
  int t = threadIdx.x;
  lh[t] = 0;
  int i = blockIdx.x*256 + t;
  int v = 0;
  if (i < NN){
    int4 cc = ((const int4*)cnt4)[i];
    v = cc.x + cc.y + cc.z + cc.w;
    int4 so;
    so.x = 0; so.y = cc.x; so.z = cc.x + cc.y; so.w = cc.x + cc.y + cc.z;
    ((int4*)shoff)[i] = so;
  }
  sm[t] = v;
  __syncthreads();
  if (i < NN) atomicAdd(&lh[v > 255 ? 255 : v], 1);   // degree histogram
  for (int off=1; off<256; off<<=1){
    int u = (t>=off) ? sm[t-off] : 0;
    __syncthreads();
    sm[t] += u;
    __syncthreads();
  }
  if (i < NN) rowptr[i] = sm[t] - v;
  if (t == 255) bsum[blockIdx.x] = sm[255];
  __syncthreads();
  if (lh[t] > 0) atomicAdd(&dbin[t], lh[t]);
}

// ---------------- scan_finish + dscan (merged; last block scans dbin) ----------------

__global__ __launch_bounds__(512) void k_scan_finish(int* __restrict__ rowptr, const int* __restrict__ bsum,
                                                     int* __restrict__ dbin){
  __shared__ int sm[512];
  int t = threadIdx.x;
  if (blockIdx.x == NF_SCAN){
    int v = (t < 256) ? dbin[t] : 0;
    sm[t] = v;
    __syncthreads();
    for (int off=1; off<512; off<<=1){
      int u = (t>=off) ? sm[t-off] : 0;
      __syncthreads();
      sm[t] += u;
      __syncthreads();
    }
    if (t < 256) dbin[t] = sm[t] - v;   // exclusive
    return;
  }
  __shared__ int ex[512];
  int v = (t < NB_SCAN) ? bsum[t] : 0;
  sm[t] = v;
  __syncthreads();
  for (int off=1; off<512; off<<=1){
    int u = (t>=off) ? sm[t-off] : 0;
    __syncthreads();
    sm[t] += u;
    __syncthreads();
  }
  ex[t] = sm[t] - v;
  __syncthreads();
  int i = blockIdx.x*512 + t;
  if (i < NN) rowptr[i] += ex[i>>8];
  else if (i == NN) rowptr[NN] = NE;
}

// ---------------- CSR placement (ILP-4) MERGED with perm scatter ----------------

__global__ __launch_bounds__(256) void k_place_dscat(const int* __restrict__ src, const int* __restrict__ dst,
                                                     const int* __restrict__ rowptr, const int* __restrict__ shoff,
                                                     const int* __restrict__ tick, int* __restrict__ csr,
                                                     int* __restrict__ dbin, int* __restrict__ perm){
  int bid = blockIdx.x, t = threadIdx.x;
  if (bid < TICKET4_BLOCKS){
    int idx = bid*256 + t;
    if (idx < NE/4){
      int e0 = idx*4;
      int4 s4 = *(const int4*)(src + e0);
      int4 d4 = *(const int4*)(dst + e0);
      int4 t4 = *(const int4*)(tick + e0);
      csr[rowptr[d4.x] + shoff[(uint)d4.x*4u + 0u] + t4.x] = s4.x;
      csr[rowptr[d4.y] + shoff[(uint)d4.y*4u + 1u] + t4.y] = s4.y;
      csr[rowptr[d4.z] + shoff[(uint)d4.z*4u + 2u] + t4.z] = s4.z;
      csr[rowptr[d4.w] + shoff[(uint)d4.w*4u + 3u] + t4.w] = s4.w;
    }
  } else {
    __shared__ int lh[256];
    __shared__ int lbase[256];
    lh[t] = 0;
    __syncthreads();
    int n = (bid - TICKET4_BLOCKS)*256 + t;
    int bin = -1, lticket = 0;
    if (n < NN){
      int deg = rowptr[n+1] - rowptr[n];
      bin = deg > 255 ? 255 : deg;
      lticket = atomicAdd(&lh[bin], 1);
    }
    __syncthreads();
    if (lh[t] > 0) lbase[t] = atomicAdd(&dbin[t], lh[t]);
    __syncthreads();
    if (n < NN) perm[lbase[bin] + lticket] = n;
  }
}

// ---------------- MFMA GEMM, K=128, 512 threads, 128 rows/block, B in LDS ----------------

template<int NT, int NTF, int H>
__global__ __launch_bounds__(512) void k_gemm_mfma(const ushort* __restrict__ Ab, const ushort* __restrict__ Bf,
                                                   ushort* __restrict__ featb, float* __restrict__ Cres,
                                                   const float* __restrict__ al, const float* __restrict__ ar,
                                                   float* __restrict__ el, float* __restrict__ er, int M){
  __shared__ ushort Bs[NT*2048];
  int t = threadIdx.x;
  #pragma unroll
  for (int i=0; i<NT/2; ++i)
    ((uint4*)Bs)[i*512 + t] = ((const uint4*)Bf)[i*512 + t];
  __syncthreads();

  int l = t & 63, w = t >> 6;              // w = 0..7
  int rw = blockIdx.x*128 + w*16;
  int c = l & 15, g = l >> 4;

  f32x4 acc[NT];
  #pragma unroll
  for (int nt=0;nt<NT;nt++) acc[nt] = (f32x4){0.f,0.f,0.f,0.f};

  int rowA = rw + c; if (rowA >= M) rowA = M-1;
  const ushort* Ap = Ab + (size_t)rowA*128 + g*8;
  const bfrag* Bp = (const bfrag*)Bs;

  #pragma unroll
  for (int ks=0; ks<4; ++ks){
    bfrag a = *(const bfrag*)(Ap + ks*32);
    #pragma unroll
    for (int nt=0; nt<NT; ++nt){
      bfrag b = Bp[(nt*4+ks)*64 + l];
      acc[nt] = __builtin_amdgcn_mfma_f32_16x16x32_bf16(a, b, acc[nt], 0, 0, 0);
    }
  }

  float alv[H][2], arv[H][2];
  #pragma unroll
  for (int h=0;h<H;h++){
    alv[h][0]=al[h*32+c]*LOG2E;    arv[h][0]=ar[h*32+c]*LOG2E;
    alv[h][1]=al[h*32+16+c]*LOG2E; arv[h][1]=ar[h*32+16+c]*LOG2E;
  }

  #pragma unroll
  for (int reg=0; reg<4; ++reg){
    int row = rw + g*4 + reg;
    bool ok = row < M;
    #pragma unroll
    for (int h=0;h<H;h++){
      float pl = acc[2*h][reg]*alv[h][0] + acc[2*h+1][reg]*alv[h][1];
      float pr = acc[2*h][reg]*arv[h][0] + acc[2*h+1][reg]*arv[h][1];
      #pragma unroll
      for (int off=1; off<16; off<<=1){ pl += __shfl_xor(pl,off); pr += __shfl_xor(pr,off); }
      if (ok && c==0){ el[(size_t)row*H + h] = pl; er[(size_t)row*H + h] = pr; }
    }
    if (ok){
      #pragma unroll
      for (int nt=0; nt<NTF; ++nt)
        featb[(size_t)row*(NTF*16) + nt*16 + c] = f2bf(acc[nt][reg]);
      #pragma unroll
      for (int nt=NTF; nt<NT; ++nt)
        Cres[(size_t)row*((NT-NTF)*16) + (nt-NTF)*16 + c] = acc[nt][reg];
    }
  }
}

// ---------------- aggregation H=4: 4 nodes/wave, 16 lanes/node, no reductions ----------------

template<int RK>
__global__ __launch_bounds__(256) void k_agg4(const int* __restrict__ rowptr, const int* __restrict__ csr,
                                              const int* __restrict__ perm,
                                              const ushort* __restrict__ feat,
                                              const float* __restrict__ el, const float* __restrict__ er,
                                              const void* __restrict__ res, const float* __restrict__ bias,
                                              ushort* __restrict__ out, int act){
  int t = threadIdx.x;
  int l15 = t & 15;
  int node = perm[blockIdx.x*16 + (t>>4)];

  int beg = rowptr[node], deg = rowptr[node+1] - beg;
  int hm = l15 >> 2;
  float erh = er[(size_t)node*4 + hm];
  const int* cp = csr + beg;
  uint fo = (uint)l15*8u;

  float ssum = 0.f;
  float a0=0.f,a1=0.f,a2=0.f,a3=0.f,a4=0.f,a5=0.f,a6=0.f,a7=0.f;

  int ei = 0;
  for (; ei+4 <= deg; ei += 4){
    int s0 = cp[ei], s1 = cp[ei+1], s2 = cp[ei+2], s3 = cp[ei+3];
    uint4 p0 = *(const uint4*)(feat + ((uint)s0*128u + fo));
    uint4 p1 = *(const uint4*)(feat + ((uint)s1*128u + fo));
    uint4 p2 = *(const uint4*)(feat + ((uint)s2*128u + fo));
    uint4 p3 = *(const uint4*)(feat + ((uint)s3*128u + fo));
    float v0 = el[(uint)s0*4u + hm] + erh; v0 = fmaxf(v0, 0.2f*v0);
    float v1 = el[(uint)s1*4u + hm] + erh; v1 = fmaxf(v1, 0.2f*v1);
    float v2 = el[(uint)s2*4u + hm] + erh; v2 = fmaxf(v2, 0.2f*v2);
    float v3 = el[(uint)s3*4u + hm] + erh; v3 = fmaxf(v3, 0.2f*v3);
    float w0 = __builtin_amdgcn_exp2f(v0);
    float w1 = __builtin_amdgcn_exp2f(v1);
    float w2 = __builtin_amdgcn_exp2f(v2);
    float w3 = __builtin_amdgcn_exp2f(v3);
    ssum += (w0 + w1) + (w2 + w3);
    a0 += w0*bflo(p0.x) + w1*bflo(p1.x) + w2*bflo(p2.x) + w3*bflo(p3.x);
    a1 += w0*bfhi(p0.x) + w1*bfhi(p1.x) + w2*bfhi(p2.x) + w3*bfhi(p3.x);
    a2 += w0*bflo(p0.y) + w1*bflo(p1.y) + w2*bflo(p2.y) + w3*bflo(p3.y);
    a3 += w0*bfhi(p0.y) + w1*bfhi(p1.y) + w2*bfhi(p2.y) + w3*bfhi(p3.y);
    a4 += w0*bflo(p0.z) + w1*bflo(p1.z) + w2*bflo(p2.z) + w3*bflo(p3.z);
    a5 += w0*bfhi(p0.z) + w1*bfhi(p1.z) + w2*bfhi(p2.z) + w3*bfhi(p3.z);
    a6 += w0*bflo(p0.w) + w1*bflo(p1.w) + w2*bflo(p2.w) + w3*bflo(p3.w);
    a7 += w0*bfhi(p0.w) + w1*bfhi(p1.w) + w2*bfhi(p2.w) + w3*bfhi(p3.w);
  }
  for (; ei < deg; ++ei){
    int s0 = cp[ei];
    uint4 p0 = *(const uint4*)(feat + ((uint)s0*128u + fo));
    float v0 = el[(uint)s0*4u + hm] + erh; v0 = fmaxf(v0, 0.2f*v0);
    float w0 = __builtin_amdgcn_exp2f(v0);
    ssum += w0;
    a0 += w0*bflo(p0.x); a1 += w0*bfhi(p0.x);
    a2 += w0*bflo(p0.y); a3 += w0*bfhi(p0.y);
    a4 += w0*bflo(p0.z); a5 += w0*bfhi(p0.z);
    a6 += w0*bflo(p0.w); a7 += w0*bfhi(p0.w);
  }

  float inv = (deg > 0) ? 1.f/ssum : 0.f;
  float o0=a0*inv, o1=a1*inv, o2=a2*inv, o3=a3*inv;
  float o4=a4*inv, o5=a5*inv, o6=a6*inv, o7=a7*inv;
  if (RK == 1){
    uint4 rv = *(const uint4*)((const ushort*)res + (size_t)node*128 + fo);
    o0 += bflo(rv.x); o1 += bfhi(rv.x); o2 += bflo(rv.y); o3 += bfhi(rv.y);
    o4 += bflo(rv.z); o5 += bfhi(rv.z); o6 += bflo(rv.w); o7 += bfhi(rv.w);
  }
  float4 bv0 = *(const float4*)(bias + l15*8);
  float4 bv1 = *(const float4*)(bias + l15*8 + 4);
  o0 += bv0.x; o1 += bv0.y; o2 += bv0.z; o3 += bv0.w;
  o4 += bv1.x; o5 += bv1.y; o6 += bv1.z; o7 += bv1.w;
  if (act){
    o0 = (o0>0.f)?o0:__expf(o0)-1.f;
    o1 = (o1>0.f)?o1:__expf(o1)-1.f;
    o2 = (o2>0.f)?o2:__expf(o2)-1.f;
    o3 = (o3>0.f)?o3:__expf(o3)-1.f;
    o4 = (o4>0.f)?o4:__expf(o4)-1.f;
    o5 = (o5>0.f)?o5:__expf(o5)-1.f;
    o6 = (o6>0.f)?o6:__expf(o6)-1.f;
    o7 = (o7>0.f)?o7:__expf(o7)-1.f;
  }
  uint4 pk;
  pk.x = (uint)f2bf(o0) | ((uint)f2bf(o1)<<16);
  pk.y = (uint)f2bf(o2) | ((uint)f2bf(o3)<<16);
  pk.z = (uint)f2bf(o4) | ((uint)f2bf(o5)<<16);
  pk.w = (uint)f2bf(o6) | ((uint)f2bf(o7)<<16);
  *(uint4*)(out + (size_t)node*128 + fo) = pk;
}

// ---------------- aggregation H=1: 8 nodes/wave, 8 lanes/node ----------------

__global__ __launch_bounds__(256) void k_agg1(const int* __restrict__ rowptr, const int* __restrict__ csr,
                                              const int* __restrict__ perm,
                                              const ushort* __restrict__ feat,
                                              const float* __restrict__ el, const float* __restrict__ er,
                                              const float* __restrict__ res, const float* __restrict__ bias,
                                              float* __restrict__ h3){
  int t = threadIdx.x;
  int l7 = t & 7;
  int node = perm[blockIdx.x*32 + (t>>3)];

  int beg = rowptr[node], deg = rowptr[node+1] - beg;
  float er0 = er[node];
  const int* cp = csr + beg;
  uint fo = (uint)l7*4u;

  float ssum = 0.f, a0=0.f, a1=0.f, a2=0.f, a3=0.f;
  int ei = 0;
  for (; ei+2 <= deg; ei += 2){
    int s0 = cp[ei], s1 = cp[ei+1];
    uint2 p0 = *(const uint2*)(feat + ((uint)s0*32u + fo));
    uint2 p1 = *(const uint2*)(feat + ((uint)s1*32u + fo));
    float v0 = el[s0] + er0; v0 = fmaxf(v0, 0.2f*v0);
    float v1 = el[s1] + er0; v1 = fmaxf(v1, 0.2f*v1);
    float w0 = __builtin_amdgcn_exp2f(v0);
    float w1 = __builtin_amdgcn_exp2f(v1);
    ssum += w0 + w1;
    a0 += w0*bflo(p0.x) + w1*bflo(p1.x);
    a1 += w0*bfhi(p0.x) + w1*bfhi(p1.x);
    a2 += w0*bflo(p0.y) + w1*bflo(p1.y);
    a3 += w0*bfhi(p0.y) + w1*bfhi(p1.y);
  }
  if (ei < deg){
    int s0 = cp[ei];
    uint2 p0 = *(const uint2*)(feat + ((uint)s0*32u + fo));
    float v0 = el[s0] + er0; v0 = fmaxf(v0, 0.2f*v0);
    float w0 = __builtin_amdgcn_exp2f(v0);
    ssum += w0;
    a0 += w0*bflo(p0.x); a1 += w0*bfhi(p0.x);
    a2 += w0*bflo(p0.y); a3 += w0*bfhi(p0.y);
  }

  float inv = (deg > 0) ? 1.f/ssum : 0.f;
  float4 rv = *(const float4*)(res + (size_t)node*32 + fo);
  float4 bv = *(const float4*)(bias + fo);
  float4 ov;
  ov.x = a0*inv + rv.x + bv.x;
  ov.y = a1*inv + rv.y + bv.y;
  ov.z = a2*inv + rv.z + bv.z;
  ov.w = a3*inv + rv.w + bv.w;
  *(float4*)(h3 + (size_t)node*32 + fo) = ov;
}

// ---------------- final FC: out[N,40] = h[N,32] @ Wfc[32,40] + bfc ----------------

__global__ __launch_bounds__(256) void k_fc(const float* __restrict__ h, const float* __restrict__ W,
                                            const float* __restrict__ b, float* __restrict__ out){
  __shared__ float Ws[32*40];
  __shared__ float Hs[64][33];
  __shared__ float bs[40];
  int t = threadIdx.x;
  for (int i=t; i<1280; i+=256) Ws[i] = W[i];
  if (t < 40) bs[t] = b[t];
  int n0 = blockIdx.x*64;
  for (int idx=t; idx<512; idx+=256){
    int r = idx>>3, c4 = idx&7;
    float4 v;
    if (n0 + r < NN) v = *(const float4*)(h + (size_t)(n0+r)*32 + c4*4);
    else v = make_float4(0.f,0.f,0.f,0.f);
    Hs[r][c4*4+0]=v.x; Hs[r][c4*4+1]=v.y; Hs[r][c4*4+2]=v.z; Hs[r][c4*4+3]=v.w;
  }
  __syncthreads();
  int n = t>>2, cg = t&3;
  float acc[10];
  #pragma unroll
  for (int j=0;j<10;j++) acc[j] = 0.f;
  #pragma unroll
  for (int k=0;k<32;k++){
    float hv = Hs[n][k];
    #pragma unroll
    for (int j=0;j<10;j++) acc[j] += hv * Ws[k*40 + cg + 4*j];
  }
  int row = n0 + n;
  if (row < NN){
    #pragma unroll
    for (int j=0;j<10;j++) out[(size_t)row*40 + cg + 4*j] = acc[j] + bs[cg+4*j];
  }
}

// ---------------- launch ----------------

extern "C" void kernel_launch(void* const* d_in, const int* in_sizes, int n_in,
                              void* d_out, int out_size, void* d_ws, size_t ws_size,
                              hipStream_t stream){
  const float* x    = (const float*)d_in[0];
  const int*   src  = (const int*)  d_in[1];
  const int*   dst  = (const int*)  d_in[2];
  const float* W1   = (const float*)d_in[3];
  const float* al1  = (const float*)d_in[4];
  const float* ar1  = (const float*)d_in[5];
  const float* b1   = (const float*)d_in[6];
  const float* W2   = (const float*)d_in[7];
  const float* al2  = (const float*)d_in[8];
  const float* ar2  = (const float*)d_in[9];
  const float* b2   = (const float*)d_in[10];
  const float* W3   = (const float*)d_in[11];
  const float* al3  = (const float*)d_in[12];
  const float* ar3  = (const float*)d_in[13];
  const float* b3   = (const float*)d_in[14];
  const float* res3 = (const float*)d_in[15];
  const float* Wfc  = (const float*)d_in[16];
  const float* bfc  = (const float*)d_in[17];
  float* out = (float*)d_out;

  char* ws = (char*)d_ws;
  size_t o = 0;
  auto alloc = [&](size_t bytes)->char*{
    char* p = ws + o;
    o += (bytes + 255) & ~(size_t)255;
    return p;
  };
  int*    rowptr = (int*)   alloc((size_t)(NN+1)*4);
  int*    cnt4   = (int*)   alloc((size_t)NN*4*4);
  int*    shoff  = (int*)   alloc((size_t)NN*4*4);
  int*    bsum   = (int*)   alloc(512*4);
  int*    dbin   = (int*)   alloc(256*4);
  int*    perm   = (int*)   alloc((size_t)NN*4);
  int*    tick   = (int*)   alloc((size_t)NE*4);
  int*    csr    = (int*)   alloc((size_t)NE*4);
  float*  el     = (float*) alloc((size_t)NN*4*4);
  float*  er     = (float*) alloc((size_t)NN*4*4);
  ushort* featb  = (ushort*)alloc((size_t)NN*128*2);
  ushort* h1b    = (ushort*)alloc((size_t)NN*128*2);
  ushort* h2b    = (ushort*)alloc((size_t)NN*128*2);
  float*  res3p  = (float*) alloc((size_t)NN*32*4);
  float*  h3     = (float*) alloc((size_t)NN*32*4);
  ushort* Bf1    = (ushort*)alloc((size_t)8*4*64*8*2);
  ushort* Bf2    = (ushort*)alloc((size_t)8*4*64*8*2);
  ushort* Bf3    = (ushort*)alloc((size_t)4*4*64*8*2);
  (void)ws_size; (void)n_in; (void)in_sizes; (void)out_size;

  // prep0: weight packs + zero cnt4/dbin
  k_prep0<<<20+NB_SCAN+1, 256, 0, stream>>>(W1, W2, W3, res3, Bf1, Bf2, Bf3, cnt4, dbin);

  // ---- Layer-1 GEMM (fused cast) 2:5-interleaved with ILP-1 ticket atomics ----
  k_gemm1_ticket<<<MERGED_BLOCKS, 256, 0, stream>>>(x, Bf1, featb, al1, ar1, el, er,
                                                    dst, cnt4, tick);

  // scans (+ degree hist folded into scan_local, dscan folded into scan_finish)
  k_scan_local<<<NB_SCAN, 256, 0, stream>>>(cnt4, shoff, rowptr, bsum, dbin);
  k_scan_finish<<<NF_SCAN+1, 512, 0, stream>>>(rowptr, bsum, dbin);

  // CSR placement (ILP-4) overlapped with perm scatter
  k_place_dscat<<<TICKET4_BLOCKS+NB_SCAN, 256, 0, stream>>>(src, dst, rowptr, shoff, tick, csr,
                                                            dbin, perm);

  // ---- Layer 1 aggregation ----
  k_agg4<0><<<NN/16, 256, 0, stream>>>(rowptr, csr, perm, featb, el, er, nullptr, b1, h1b, 1);

  // ---- Layer 2 ----
  k_gemm_mfma<8,8,4><<<GEMM2_BLOCKS, 512, 0, stream>>>(h1b, Bf2, featb, nullptr, al2, ar2, el, er, NN);
  k_agg4<1><<<NN/16, 256, 0, stream>>>(rowptr, csr, perm, featb, el, er, h1b, b2, h2b, 1);

  // ---- Layer 3 ----
  k_gemm_mfma<4,2,1><<<GEMM2_BLOCKS, 512, 0, stream>>>(h2b, Bf3, featb, res3p, al3, ar3, el, er, NN);
  k_agg1<<<NN/32, 256, 0, stream>>>(rowptr, csr, perm, featb, el, er, res3p, b3, h3);
  k_fc<<<GEMM_BLOCKS, 256, 0, stream>>>(h3, Wfc, bfc, out);
}